// Round 12
// baseline (79.435 us; speedup 1.0000x reference)
//
#include <hip/hip_runtime.h>
#include <math.h>

#define HW    64
#define NPIX  32768

typedef __attribute__((ext_vector_type(8))) short bf16x8;
typedef __attribute__((ext_vector_type(8))) short short8v;
typedef __attribute__((ext_vector_type(4))) float f32x4;

static __device__ inline short f2bf(float f) {
    union { float f; unsigned u; } v; v.f = f;
    unsigned r = v.u + 0x7fff + ((v.u >> 16) & 1);   // RNE
    return (short)(r >> 16);
}
static __device__ inline float bf2f(short s) {
    union { unsigned u; float f; } v; v.u = ((unsigned)(unsigned short)s) << 16;
    return v.f;
}

// ---------------------------------------------------------------------------
// k_misc: blocks [0,512) = transpose x NCHW f32 -> NHWC bf16 (proven r10 body);
//         blocks [512,728) = weight prep:
//           wt3: lane-major main-weight frags [wv][f][kk][lane][8]  (73,728 B)
//           wc2: [f][ch32][c] off+mod conv weights (unchanged)
// ---------------------------------------------------------------------------
__global__ __launch_bounds__(256) void k_misc(
        const float* __restrict__ x, short* __restrict__ xt,
        const float* __restrict__ w, const float* __restrict__ w_off,
        const float* __restrict__ w_mod,
        short* __restrict__ wt3, short* __restrict__ wc2) {
    int tid = threadIdx.x;
    if (blockIdx.x < 512) {
        __shared__ float s[64 * 65];
        int by = blockIdx.x;
        int b = by >> 6, y = by & 63;
        const float* xb = x + ((size_t)b * 64) * 4096 + y * 64;
        #pragma unroll
        for (int q = 0; q < 4; ++q) {
            int fi = q * 256 + tid;
            int c = fi >> 4, xq = (fi & 15) * 4;
            float4 v = *(const float4*)(xb + (size_t)c * 4096 + xq);
            s[c * 65 + xq + 0] = v.x; s[c * 65 + xq + 1] = v.y;
            s[c * 65 + xq + 2] = v.z; s[c * 65 + xq + 3] = v.w;
        }
        __syncthreads();
        short* dst = xt + ((size_t)(b * 64 + y)) * 4096;
        #pragma unroll
        for (int q = 0; q < 4; ++q) {
            int fi = q * 256 + tid;
            int xx = fi >> 4, c = (fi & 15) * 4;
            short4 v = make_short4(f2bf(s[(c + 0) * 65 + xx]), f2bf(s[(c + 1) * 65 + xx]),
                                   f2bf(s[(c + 2) * 65 + xx]), f2bf(s[(c + 3) * 65 + xx]));
            *(short4*)(dst + xx * 64 + c) = v;
        }
    } else {
        int t = (blockIdx.x - 512) * 256 + tid;      // 0 .. 55295
        if (t < 36864) {
            // wt3[t]: t = wv*9216 + f*1024 + kk*512 + lane*8 + j
            int wv = t / 9216, r = t - wv * 9216;
            int f  = r >> 10;
            int r2 = r & 1023;
            int kk = r2 >> 9, lane = (r2 >> 3) & 63, j = r2 & 7;
            int o = wv * 16 + (lane & 15);
            int c = kk * 32 + (lane >> 4) * 8 + j;
            wt3[t] = f2bf(w[(o * 64 + c) * 9 + f]);
        }
        int u = t - 36864;
        if (u >= 0 && u < 9 * 32 * 64) {
            int c = u & 63, ch = (u >> 6) & 31, f = u >> 11;
            float v = 0.f;
            if (ch < 18)      v = w_off[(ch * 64 + c) * 9 + f];
            else if (ch < 27) v = w_mod[((ch - 18) * 64 + c) * 9 + f];
            wc2[u] = f2bf(v);
        }
    }
}

// ---------------------------------------------------------------------------
// conv+meta kernel: per full row (b,i), 256 thr / 4 waves (unchanged, proven).
// metaO = byte offsets of the 4 clamped corner rows within xt[b].
// ---------------------------------------------------------------------------
__global__ __launch_bounds__(256) void k_convmeta(
        const short* __restrict__ xt, const short* __restrict__ wc2,
        const float* __restrict__ b_off, const float* __restrict__ b_mod,
        float4* __restrict__ metaW, int4* __restrict__ metaO) {
    __shared__ __align__(16) char smem[34816];
    float* s_out = (float*)(smem + 26112);           // [32ch][66]

    int tid  = threadIdx.x;
    int lane = tid & 63;
    int wv   = __builtin_amdgcn_readfirstlane((int)(tid >> 6));
    int blk  = blockIdx.x;                           // b*64 + i
    int b = blk >> 6, i = blk & 63;
    const short* xs = xt + (size_t)b * 262144;

    int arow = lane & 15, cg = lane >> 4, cgb = cg * 8;

    for (int u = tid; u < 1632; u += 256) {          // 204 cells x 8 chunks
        int cell = u >> 3, chunk = u & 7;
        int r = cell / 68, cc = cell - r * 68;
        int y = i - 1 + r, gx = cc - 2;
        short8v v = (short8v){0,0,0,0,0,0,0,0};
        if (((unsigned)y < 64u) & ((unsigned)gx < 64u))
            v = *(const short8v*)(xs + ((y << 6) + gx) * 64 + chunk * 8);
        *(short8v*)(smem + cell * 128 + ((chunk * 16) ^ ((cell & 7) << 4))) = v;
    }
    __syncthreads();

    {
        int nf = wv & 1, mg = wv >> 1;
        f32x4 accc[2];
        accc[0] = (f32x4){0.f,0.f,0.f,0.f};
        accc[1] = (f32x4){0.f,0.f,0.f,0.f};
        #pragma unroll
        for (int ky = 0; ky < 3; ++ky)
            #pragma unroll
            for (int kx = 0; kx < 3; ++kx) {
                int f = ky * 3 + kx;
                #pragma unroll
                for (int kk = 0; kk < 2; ++kk) {
                    bf16x8 bq = *(const bf16x8*)(wc2 + (f * 32 + nf * 16 + arow) * 64
                                                 + kk * 32 + cgb);
                    #pragma unroll
                    for (int mm = 0; mm < 2; ++mm) {
                        int cell = ky * 68 + mg * 32 + mm * 16 + arow + kx + 1;
                        const char* ap = smem + cell * 128
                                       + ((kk * 64 + cg * 16) ^ ((cell & 7) << 4));
                        accc[mm] = __builtin_amdgcn_mfma_f32_16x16x32_bf16(
                            *(const bf16x8*)ap, bq, accc[mm], 0, 0, 0);
                    }
                }
            }
        #pragma unroll
        for (int mm = 0; mm < 2; ++mm)
            #pragma unroll
            for (int r = 0; r < 4; ++r)
                s_out[(nf * 16 + arow) * 66 + mg * 32 + mm * 16 + cg * 4 + r] = accc[mm][r];
    }
    __syncthreads();

    int pixBase = blk * 64;
    for (int u = tid; u < 576; u += 256) {
        int f = u >> 6, p = u & 63;
        float dy = s_out[(2 * f)     * 66 + p] + b_off[2 * f];
        float dx = s_out[(2 * f + 1) * 66 + p] + b_off[2 * f + 1];
        float mv = s_out[(18 + f)    * 66 + p] + b_mod[f];
        float m  = 1.f / (1.f + expf(-mv));

        float ys  = (float)(i - 1 + f / 3) + dy;
        float xs2 = (float)(p - 1 + f % 3) + dx;
        float y0f = floorf(ys), x0f = floorf(xs2);
        int   y0  = (int)y0f,   x0  = (int)x0f;
        float fy = ys - y0f, fx = xs2 - x0f;

        bool vy0 = (unsigned)y0       < 64u, vy1 = (unsigned)(y0 + 1) < 64u;
        bool vx0 = (unsigned)x0       < 64u, vx1 = (unsigned)(x0 + 1) < 64u;
        float w00 = (vy0 & vx0) ? (1.f - fy) * (1.f - fx) * m : 0.f;
        float w01 = (vy0 & vx1) ? (1.f - fy) * fx         * m : 0.f;
        float w10 = (vy1 & vx0) ? fy         * (1.f - fx) * m : 0.f;
        float w11 = (vy1 & vx1) ? fy         * fx         * m : 0.f;

        int y0c = min(max(y0, 0), 63), y1c = min(max(y0 + 1, 0), 63);
        int x0c = min(max(x0, 0), 63), x1c = min(max(x0 + 1, 0), 63);

        metaW[f * NPIX + pixBase + p] = make_float4(w00, w01, w10, w11);
        metaO[f * NPIX + pixBase + p] = make_int4(((y0c << 6) + x0c) * 128,
                                                  ((y0c << 6) + x1c) * 128,
                                                  ((y1c << 6) + x0c) * 128,
                                                  ((y1c << 6) + x1c) * 128);
    }
}

// ---------------------------------------------------------------------------
// k_deform: FUSED sample + GEMM through LDS (no global S).
// Block = 32 px x 64 Cout, 256 thr / 4 waves, grid 1024 (4 blocks/CU).
//  phase A: each wave samples 8 px x 9 taps (r11 bug: was 4 px -> rows 16..31
//           uninitialized -> NaN); per task: uniform s_load meta, 4 coalesced
//           128 B corner loads (lane = channel), interp, swizzled ds_write.
//  (one barrier)
//  phase B: GEMM out[px][o] = S[px][f,c] * W[o][f,c], K = 576:
//           B-frags = 18 coalesced 1 KB loads from lane-major wt3 (72 VGPR),
//           36 MFMA/wave from swizzled LDS (2-way worst, free).
//  epilogue: LDS transpose (aliases S-tile) -> coalesced float4 stores.
// ---------------------------------------------------------------------------
__global__ __launch_bounds__(256, 4) void k_deform(
        const short* __restrict__ xt,
        const float4* __restrict__ metaW, const int4* __restrict__ metaO,
        const short* __restrict__ wt3, const float* __restrict__ bias,
        float* __restrict__ out) {
    __shared__ __align__(16) char smem[36864];       // S-tile [32][1152 B]; s_fin aliases
    float* s_fin = (float*)smem;                     // [64 o][33] f32 (epilogue)

    int tid  = threadIdx.x;
    int lane = tid & 63;
    int wv   = __builtin_amdgcn_readfirstlane((int)(tid >> 6));
    int blk  = blockIdx.x;                           // (b*64+i)*2 + half
    int b = blk >> 7, i = (blk >> 1) & 63, jb = (blk & 1) * 32;
    int P0 = blk * 32;
    int arow = lane & 15, cg = lane >> 4;

    // ---- B-frags first (independent; latency hidden under sample phase)
    bf16x8 bfrag[9][2];
    #pragma unroll
    for (int f = 0; f < 9; ++f)
        #pragma unroll
        for (int kk = 0; kk < 2; ++kk)
            bfrag[f][kk] = *(const bf16x8*)(wt3 + ((wv * 18 + f * 2 + kk) * 64 + lane) * 8);

    // ---- phase A: sample 8 px x 9 taps per wave -> swizzled LDS S-tile
    #pragma unroll
    for (int pp = 0; pp < 8; ++pp) {
        int px = wv * 8 + pp;                        // wave-uniform, covers 0..31
        int P  = P0 + px;
        const char* xbb = (const char*)(xt + ((size_t)(P >> 12)) * 262144);
        int rowbase = px * 1152;
        int swz = (px & 7) << 4;
        #pragma unroll
        for (int f = 0; f < 9; ++f) {
            float4 mW = metaW[f * NPIX + P];         // uniform -> s_load
            int4   mO = metaO[f * NPIX + P];
            short c0 = *(const short*)(xbb + mO.x + lane * 2);
            short c1 = *(const short*)(xbb + mO.y + lane * 2);
            short c2 = *(const short*)(xbb + mO.z + lane * 2);
            short c3 = *(const short*)(xbb + mO.w + lane * 2);
            float s = mW.x * bf2f(c0) + mW.y * bf2f(c1)
                    + mW.z * bf2f(c2) + mW.w * bf2f(c3);
            *(short*)(smem + rowbase + f * 128 + ((lane * 2) ^ swz)) = f2bf(s);
        }
    }
    __syncthreads();

    // ---- phase B: GEMM, K = 576 (9 taps x 64 ch)
    f32x4 acc[2];
    acc[0] = (f32x4){0.f,0.f,0.f,0.f};
    acc[1] = (f32x4){0.f,0.f,0.f,0.f};
    #pragma unroll
    for (int f = 0; f < 9; ++f)
        #pragma unroll
        for (int kk = 0; kk < 2; ++kk)
            #pragma unroll
            for (int mf = 0; mf < 2; ++mf) {
                int px = mf * 16 + arow;
                const char* ap = smem + px * 1152 + f * 128
                               + ((kk * 64 + cg * 16) ^ ((px & 7) << 4));
                acc[mf] = __builtin_amdgcn_mfma_f32_16x16x32_bf16(
                    *(const bf16x8*)ap, bfrag[f][kk], acc[mf], 0, 0, 0);
            }
    __syncthreads();                                 // S-tile dead; s_fin aliases

    // ---- epilogue: acc (col=o, row=px) -> s_fin[o][px] -> coalesced store
    {
        int o = wv * 16 + arow;
        #pragma unroll
        for (int mf = 0; mf < 2; ++mf)
            #pragma unroll
            for (int r = 0; r < 4; ++r)
                s_fin[o * 33 + mf * 16 + cg * 4 + r] = acc[mf][r];
    }
    __syncthreads();
    {
        int o = tid >> 2, q = tid & 3;
        float bv = bias[o];
        float* op = out + ((size_t)(b * 64 + o)) * 4096 + i * 64 + jb + q * 8;
        float4 v0, v1;
        v0.x = s_fin[o * 33 + q * 8 + 0] + bv;
        v0.y = s_fin[o * 33 + q * 8 + 1] + bv;
        v0.z = s_fin[o * 33 + q * 8 + 2] + bv;
        v0.w = s_fin[o * 33 + q * 8 + 3] + bv;
        v1.x = s_fin[o * 33 + q * 8 + 4] + bv;
        v1.y = s_fin[o * 33 + q * 8 + 5] + bv;
        v1.z = s_fin[o * 33 + q * 8 + 6] + bv;
        v1.w = s_fin[o * 33 + q * 8 + 7] + bv;
        *(float4*)op       = v0;
        *(float4*)(op + 4) = v1;
    }
}

// ---------------------------------------------------------------------------
extern "C" void kernel_launch(void* const* d_in, const int* in_sizes, int n_in,
                              void* d_out, int out_size, void* d_ws, size_t ws_size,
                              hipStream_t stream) {
    const float* x     = (const float*)d_in[0];
    const float* w_off = (const float*)d_in[1];
    const float* b_off = (const float*)d_in[2];
    const float* w_mod = (const float*)d_in[3];
    const float* b_mod = (const float*)d_in[4];
    const float* w     = (const float*)d_in[5];
    const float* bias  = (const float*)d_in[6];
    float* out = (float*)d_out;

    char* ws = (char*)d_ws;
    short*  xt    = (short*)(ws);                    //  4,194,304 B
    short*  wt3   = (short*)(ws + 4194304);          //     73,728 B
    short*  wc2   = (short*)(ws + 4268032);          //     36,864 B
    float4* metaW = (float4*)(ws + 4304896);         //  4,718,592 B
    int4*   metaO = (int4*)(ws + 9023488);           //  4,718,592 B

    hipLaunchKernelGGL(k_misc,      dim3(728),  dim3(256), 0, stream,
                       x, xt, w, w_off, w_mod, wt3, wc2);
    hipLaunchKernelGGL(k_convmeta,  dim3(512),  dim3(256), 0, stream,
                       xt, wc2, b_off, b_mod, metaW, metaO);
    hipLaunchKernelGGL(k_deform,    dim3(1024), dim3(256), 0, stream,
                       xt, metaW, metaO, wt3, bias, out);
}

// Round 13
// 67.892 us; speedup vs baseline: 1.1700x; 1.1700x over previous
//
#include <hip/hip_runtime.h>
#include <math.h>

#define HW    64
#define NPIX  32768

typedef __attribute__((ext_vector_type(8))) short bf16x8;
typedef __attribute__((ext_vector_type(8))) short short8v;
typedef __attribute__((ext_vector_type(4))) float f32x4;

static __device__ inline short f2bf(float f) {
    union { float f; unsigned u; } v; v.f = f;
    unsigned r = v.u + 0x7fff + ((v.u >> 16) & 1);   // RNE
    return (short)(r >> 16);
}
static __device__ inline float bf2f(short s) {
    union { unsigned u; float f; } v; v.u = ((unsigned)(unsigned short)s) << 16;
    return v.f;
}

// ---------------------------------------------------------------------------
// k_misc: blocks [0,512) transpose x NCHW f32 -> NHWC bf16 (proven);
//         blocks [512,728): wt3 lane-major main-weight frags + wc2 (proven).
// ---------------------------------------------------------------------------
__global__ __launch_bounds__(256) void k_misc(
        const float* __restrict__ x, short* __restrict__ xt,
        const float* __restrict__ w, const float* __restrict__ w_off,
        const float* __restrict__ w_mod,
        short* __restrict__ wt3, short* __restrict__ wc2) {
    int tid = threadIdx.x;
    if (blockIdx.x < 512) {
        __shared__ float s[64 * 65];
        int by = blockIdx.x;
        int b = by >> 6, y = by & 63;
        const float* xb = x + ((size_t)b * 64) * 4096 + y * 64;
        #pragma unroll
        for (int q = 0; q < 4; ++q) {
            int fi = q * 256 + tid;
            int c = fi >> 4, xq = (fi & 15) * 4;
            float4 v = *(const float4*)(xb + (size_t)c * 4096 + xq);
            s[c * 65 + xq + 0] = v.x; s[c * 65 + xq + 1] = v.y;
            s[c * 65 + xq + 2] = v.z; s[c * 65 + xq + 3] = v.w;
        }
        __syncthreads();
        short* dst = xt + ((size_t)(b * 64 + y)) * 4096;
        #pragma unroll
        for (int q = 0; q < 4; ++q) {
            int fi = q * 256 + tid;
            int xx = fi >> 4, c = (fi & 15) * 4;
            short4 v = make_short4(f2bf(s[(c + 0) * 65 + xx]), f2bf(s[(c + 1) * 65 + xx]),
                                   f2bf(s[(c + 2) * 65 + xx]), f2bf(s[(c + 3) * 65 + xx]));
            *(short4*)(dst + xx * 64 + c) = v;
        }
    } else {
        int t = (blockIdx.x - 512) * 256 + tid;      // 0 .. 55295
        if (t < 36864) {
            int wv = t / 9216, r = t - wv * 9216;
            int f  = r >> 10;
            int r2 = r & 1023;
            int kk = r2 >> 9, lane = (r2 >> 3) & 63, j = r2 & 7;
            int o = wv * 16 + (lane & 15);
            int c = kk * 32 + (lane >> 4) * 8 + j;
            wt3[t] = f2bf(w[(o * 64 + c) * 9 + f]);
        }
        int u = t - 36864;
        if (u >= 0 && u < 9 * 32 * 64) {
            int c = u & 63, ch = (u >> 6) & 31, f = u >> 11;
            float v = 0.f;
            if (ch < 18)      v = w_off[(ch * 64 + c) * 9 + f];
            else if (ch < 27) v = w_mod[((ch - 18) * 64 + c) * 9 + f];
            wc2[u] = f2bf(v);
        }
    }
}

// ---------------------------------------------------------------------------
// conv+meta kernel (unchanged, proven r8-r12).
// ---------------------------------------------------------------------------
__global__ __launch_bounds__(256) void k_convmeta(
        const short* __restrict__ xt, const short* __restrict__ wc2,
        const float* __restrict__ b_off, const float* __restrict__ b_mod,
        float4* __restrict__ metaW, int4* __restrict__ metaO) {
    __shared__ __align__(16) char smem[34816];
    float* s_out = (float*)(smem + 26112);           // [32ch][66]

    int tid  = threadIdx.x;
    int lane = tid & 63;
    int wv   = __builtin_amdgcn_readfirstlane((int)(tid >> 6));
    int blk  = blockIdx.x;                           // b*64 + i
    int b = blk >> 6, i = blk & 63;
    const short* xs = xt + (size_t)b * 262144;

    int arow = lane & 15, cg = lane >> 4, cgb = cg * 8;

    for (int u = tid; u < 1632; u += 256) {          // 204 cells x 8 chunks
        int cell = u >> 3, chunk = u & 7;
        int r = cell / 68, cc = cell - r * 68;
        int y = i - 1 + r, gx = cc - 2;
        short8v v = (short8v){0,0,0,0,0,0,0,0};
        if (((unsigned)y < 64u) & ((unsigned)gx < 64u))
            v = *(const short8v*)(xs + ((y << 6) + gx) * 64 + chunk * 8);
        *(short8v*)(smem + cell * 128 + ((chunk * 16) ^ ((cell & 7) << 4))) = v;
    }
    __syncthreads();

    {
        int nf = wv & 1, mg = wv >> 1;
        f32x4 accc[2];
        accc[0] = (f32x4){0.f,0.f,0.f,0.f};
        accc[1] = (f32x4){0.f,0.f,0.f,0.f};
        #pragma unroll
        for (int ky = 0; ky < 3; ++ky)
            #pragma unroll
            for (int kx = 0; kx < 3; ++kx) {
                int f = ky * 3 + kx;
                #pragma unroll
                for (int kk = 0; kk < 2; ++kk) {
                    bf16x8 bq = *(const bf16x8*)(wc2 + (f * 32 + nf * 16 + arow) * 64
                                                 + kk * 32 + cgb);
                    #pragma unroll
                    for (int mm = 0; mm < 2; ++mm) {
                        int cell = ky * 68 + mg * 32 + mm * 16 + arow + kx + 1;
                        const char* ap = smem + cell * 128
                                       + ((kk * 64 + cg * 16) ^ ((cell & 7) << 4));
                        accc[mm] = __builtin_amdgcn_mfma_f32_16x16x32_bf16(
                            *(const bf16x8*)ap, bq, accc[mm], 0, 0, 0);
                    }
                }
            }
        #pragma unroll
        for (int mm = 0; mm < 2; ++mm)
            #pragma unroll
            for (int r = 0; r < 4; ++r)
                s_out[(nf * 16 + arow) * 66 + mg * 32 + mm * 16 + cg * 4 + r] = accc[mm][r];
    }
    __syncthreads();

    int pixBase = blk * 64;
    for (int u = tid; u < 576; u += 256) {
        int f = u >> 6, p = u & 63;
        float dy = s_out[(2 * f)     * 66 + p] + b_off[2 * f];
        float dx = s_out[(2 * f + 1) * 66 + p] + b_off[2 * f + 1];
        float mv = s_out[(18 + f)    * 66 + p] + b_mod[f];
        float m  = 1.f / (1.f + expf(-mv));

        float ys  = (float)(i - 1 + f / 3) + dy;
        float xs2 = (float)(p - 1 + f % 3) + dx;
        float y0f = floorf(ys), x0f = floorf(xs2);
        int   y0  = (int)y0f,   x0  = (int)x0f;
        float fy = ys - y0f, fx = xs2 - x0f;

        bool vy0 = (unsigned)y0       < 64u, vy1 = (unsigned)(y0 + 1) < 64u;
        bool vx0 = (unsigned)x0       < 64u, vx1 = (unsigned)(x0 + 1) < 64u;
        float w00 = (vy0 & vx0) ? (1.f - fy) * (1.f - fx) * m : 0.f;
        float w01 = (vy0 & vx1) ? (1.f - fy) * fx         * m : 0.f;
        float w10 = (vy1 & vx0) ? fy         * (1.f - fx) * m : 0.f;
        float w11 = (vy1 & vx1) ? fy         * fx         * m : 0.f;

        int y0c = min(max(y0, 0), 63), y1c = min(max(y0 + 1, 0), 63);
        int x0c = min(max(x0, 0), 63), x1c = min(max(x0 + 1, 0), 63);

        metaW[f * NPIX + pixBase + p] = make_float4(w00, w01, w10, w11);
        metaO[f * NPIX + pixBase + p] = make_int4(((y0c << 6) + x0c) * 128,
                                                  ((y0c << 6) + x1c) * 128,
                                                  ((y1c << 6) + x0c) * 128,
                                                  ((y1c << 6) + x1c) * 128);
    }
}

// ---------------------------------------------------------------------------
// k_G: dense precompute G_f[pix][o] = sum_c xt[pix][c] * w[o][c][f], bf16.
// Grid (512 rows, 9 f), 256 thr / 4 waves. Stage 64px x 64c tile (swizzled),
// wave = 16-o strip, 4 m-frags x 2 kk MFMA, LDS-transpose epilogue ->
// coalesced 32 B bf16 stores. Layout G[f][32768][64].
// ---------------------------------------------------------------------------
__global__ __launch_bounds__(256) void k_G(
        const short* __restrict__ xt, const short* __restrict__ wt3,
        short* __restrict__ G) {
    __shared__ __align__(16) char smem[16640];       // stage 8192 B; s_fin [64][65]f32 aliases
    float* s_fin = (float*)smem;

    int tid  = threadIdx.x;
    int lane = tid & 63;
    int wv   = __builtin_amdgcn_readfirstlane((int)(tid >> 6));
    int rowblk = blockIdx.x;                         // b*64 + i
    int f      = blockIdx.y;
    int arow = lane & 15, cg = lane >> 4;

    // stage 64 px x 64 c (coalesced 16 B, swizzled)
    const short* src = xt + (size_t)rowblk * 4096;
    #pragma unroll
    for (int q = 0; q < 2; ++q) {
        int u = q * 256 + tid;                       // 0..511
        int px = u >> 3, ch = u & 7;
        short8v v = *(const short8v*)(src + px * 64 + ch * 8);
        *(short8v*)(smem + px * 128 + ((ch << 4) ^ ((px & 7) << 4))) = v;
    }
    bf16x8 bfrag[2];
    bfrag[0] = *(const bf16x8*)(wt3 + ((wv * 18 + f * 2 + 0) * 64 + lane) * 8);
    bfrag[1] = *(const bf16x8*)(wt3 + ((wv * 18 + f * 2 + 1) * 64 + lane) * 8);
    __syncthreads();

    f32x4 acc[4];
    #pragma unroll
    for (int mf = 0; mf < 4; ++mf) acc[mf] = (f32x4){0.f,0.f,0.f,0.f};
    #pragma unroll
    for (int kk = 0; kk < 2; ++kk)
        #pragma unroll
        for (int mf = 0; mf < 4; ++mf) {
            int px = mf * 16 + arow;
            const char* ap = smem + px * 128 + ((kk * 64 + cg * 16) ^ ((px & 7) << 4));
            acc[mf] = __builtin_amdgcn_mfma_f32_16x16x32_bf16(
                *(const bf16x8*)ap, bfrag[kk], acc[mf], 0, 0, 0);
        }
    __syncthreads();                                 // stage dead; s_fin aliases

    {   // acc: col=o(arow), row=px -> s_fin[o][px] stride 65
        int o = wv * 16 + arow;
        #pragma unroll
        for (int mf = 0; mf < 4; ++mf)
            #pragma unroll
            for (int r = 0; r < 4; ++r)
                s_fin[o * 65 + mf * 16 + cg * 4 + r] = acc[mf][r];
    }
    __syncthreads();
    {   // write G_f rows: thread = (px, 16-o chunk), 32 B bf16 stores
        int px = tid >> 2, og = (tid & 3) * 16;
        short8v v0, v1;
        #pragma unroll
        for (int k = 0; k < 8; ++k)  v0[k] = f2bf(s_fin[(og + k) * 65 + px]);
        #pragma unroll
        for (int k = 0; k < 8; ++k)  v1[k] = f2bf(s_fin[(og + 8 + k) * 65 + px]);
        short* dst = G + ((size_t)(f * NPIX + rowblk * 64 + px)) * 64 + og;
        *(short8v*)dst       = v0;
        *(short8v*)(dst + 8) = v1;
    }
}

// ---------------------------------------------------------------------------
// k_final: out[p][o] = bias[o] + sum_f sum_corner w[p,f,cn] * G_f[q(p,f,cn)][o].
// Grid 8192 (XCD-swizzled) x 256 thr; wave = 1 pixel, lane = o.
// NO LDS in hot loop, NO barriers, 36 independent coalesced 128 B loads/wave.
// ---------------------------------------------------------------------------
__global__ __launch_bounds__(256) void k_final(
        const short* __restrict__ G,
        const float4* __restrict__ metaW, const int4* __restrict__ metaO,
        const float* __restrict__ bias, float* __restrict__ out) {
    __shared__ float s_o[4 * 64];
    int tid  = threadIdx.x;
    int lane = tid & 63;
    int wv   = __builtin_amdgcn_readfirstlane((int)(tid >> 6));
    int bid  = blockIdx.x;
    int swz  = (bid & 7) * 1024 + (bid >> 3);        // bijective on 8192
    int P    = swz * 4 + wv;
    int b    = P >> 12;
    const char* Gb = (const char*)G + (size_t)b * 524288;

    float acc = 0.f;
    #pragma unroll
    for (int f = 0; f < 9; ++f) {
        float4 mW = metaW[f * NPIX + P];             // uniform -> s_load
        int4   mO = metaO[f * NPIX + P];
        const char* Gf = Gb + f * 4194304;
        float g0 = bf2f(*(const short*)(Gf + mO.x + lane * 2));
        float g1 = bf2f(*(const short*)(Gf + mO.y + lane * 2));
        float g2 = bf2f(*(const short*)(Gf + mO.z + lane * 2));
        float g3 = bf2f(*(const short*)(Gf + mO.w + lane * 2));
        acc += mW.x * g0 + mW.y * g1 + mW.z * g2 + mW.w * g3;
    }
    s_o[wv * 64 + lane] = acc;
    __syncthreads();
    if (wv == 0) {
        int P0 = swz * 4;
        int bb = P0 >> 12, i = (P0 >> 6) & 63, j0 = P0 & 63;
        float bv = bias[lane];
        float4 v;
        v.x = s_o[0 * 64 + lane] + bv;
        v.y = s_o[1 * 64 + lane] + bv;
        v.z = s_o[2 * 64 + lane] + bv;
        v.w = s_o[3 * 64 + lane] + bv;
        *(float4*)(out + ((size_t)(bb * 64 + lane)) * 4096 + i * 64 + j0) = v;
    }
}

// ---------------------------------------------------------------------------
extern "C" void kernel_launch(void* const* d_in, const int* in_sizes, int n_in,
                              void* d_out, int out_size, void* d_ws, size_t ws_size,
                              hipStream_t stream) {
    const float* x     = (const float*)d_in[0];
    const float* w_off = (const float*)d_in[1];
    const float* b_off = (const float*)d_in[2];
    const float* w_mod = (const float*)d_in[3];
    const float* b_mod = (const float*)d_in[4];
    const float* w     = (const float*)d_in[5];
    const float* bias  = (const float*)d_in[6];
    float* out = (float*)d_out;

    char* ws = (char*)d_ws;
    short*  xt    = (short*)(ws);                    //  4,194,304 B
    short*  wt3   = (short*)(ws + 4194304);          //     73,728 B
    short*  wc2   = (short*)(ws + 4268032);          //     36,864 B
    float4* metaW = (float4*)(ws + 4304896);         //  4,718,592 B
    int4*   metaO = (int4*)(ws + 9023488);           //  4,718,592 B
    short*  G     = (short*)(ws + 13742080);         // 37,748,736 B

    hipLaunchKernelGGL(k_misc,     dim3(728),     dim3(256), 0, stream,
                       x, xt, w, w_off, w_mod, wt3, wc2);
    hipLaunchKernelGGL(k_convmeta, dim3(512),     dim3(256), 0, stream,
                       xt, wc2, b_off, b_mod, metaW, metaO);
    hipLaunchKernelGGL(k_G,        dim3(512, 9),  dim3(256), 0, stream,
                       xt, wt3, G);
    hipLaunchKernelGGL(k_final,    dim3(8192),    dim3(256), 0, stream,
                       G, metaW, metaO, bias, out);
}

// Round 14
// 55.280 us; speedup vs baseline: 1.4370x; 1.2282x over previous
//
#include <hip/hip_runtime.h>
#include <math.h>

#define HW    64
#define NPIX  32768

typedef __attribute__((ext_vector_type(8))) short bf16x8;
typedef __attribute__((ext_vector_type(8))) short short8v;
typedef __attribute__((ext_vector_type(4))) float f32x4;

static __device__ inline short f2bf(float f) {
    union { float f; unsigned u; } v; v.f = f;
    unsigned r = v.u + 0x7fff + ((v.u >> 16) & 1);   // RNE
    return (short)(r >> 16);
}

// ---------------------------------------------------------------------------
// k_misc: blocks [0,512) transpose x NCHW f32 -> NHWC bf16 (proven);
//         blocks [512,728): wt3 lane-major main-weight frags + wc2 (proven).
// ---------------------------------------------------------------------------
__global__ __launch_bounds__(256) void k_misc(
        const float* __restrict__ x, short* __restrict__ xt,
        const float* __restrict__ w, const float* __restrict__ w_off,
        const float* __restrict__ w_mod,
        short* __restrict__ wt3, short* __restrict__ wc2) {
    int tid = threadIdx.x;
    if (blockIdx.x < 512) {
        __shared__ float s[64 * 65];
        int by = blockIdx.x;
        int b = by >> 6, y = by & 63;
        const float* xb = x + ((size_t)b * 64) * 4096 + y * 64;
        #pragma unroll
        for (int q = 0; q < 4; ++q) {
            int fi = q * 256 + tid;
            int c = fi >> 4, xq = (fi & 15) * 4;
            float4 v = *(const float4*)(xb + (size_t)c * 4096 + xq);
            s[c * 65 + xq + 0] = v.x; s[c * 65 + xq + 1] = v.y;
            s[c * 65 + xq + 2] = v.z; s[c * 65 + xq + 3] = v.w;
        }
        __syncthreads();
        short* dst = xt + ((size_t)(b * 64 + y)) * 4096;
        #pragma unroll
        for (int q = 0; q < 4; ++q) {
            int fi = q * 256 + tid;
            int xx = fi >> 4, c = (fi & 15) * 4;
            short4 v = make_short4(f2bf(s[(c + 0) * 65 + xx]), f2bf(s[(c + 1) * 65 + xx]),
                                   f2bf(s[(c + 2) * 65 + xx]), f2bf(s[(c + 3) * 65 + xx]));
            *(short4*)(dst + xx * 64 + c) = v;
        }
    } else {
        int t = (blockIdx.x - 512) * 256 + tid;      // 0 .. 55295
        if (t < 36864) {
            int wv = t / 9216, r = t - wv * 9216;
            int f  = r >> 10;
            int r2 = r & 1023;
            int kk = r2 >> 9, lane = (r2 >> 3) & 63, j = r2 & 7;
            int o = wv * 16 + (lane & 15);
            int c = kk * 32 + (lane >> 4) * 8 + j;
            wt3[t] = f2bf(w[(o * 64 + c) * 9 + f]);
        }
        int u = t - 36864;
        if (u >= 0 && u < 9 * 32 * 64) {
            int c = u & 63, ch = (u >> 6) & 31, f = u >> 11;
            float v = 0.f;
            if (ch < 18)      v = w_off[(ch * 64 + c) * 9 + f];
            else if (ch < 27) v = w_mod[((ch - 18) * 64 + c) * 9 + f];
            wc2[u] = f2bf(v);
        }
    }
}

// ---------------------------------------------------------------------------
// k_convmetaG: per HALF-row (b,i,jb), 256 thr / 4 waves, grid 1024.
//  ph1: stage rows i-1..i+1 x cols jb-2..jb+33 (3x36 cells x 128 B, swizzled)
//  ph2: offset/mask conv MFMA (wave = (px-half, ch-half)) -> s_out[32ch][36]
//  ph3: bilinear meta -> global metaW/metaO (corner byte offsets, STRIDED loop)
//  ph4: G-GEMM from center staged row: G_f[px][o] = sum_c xt[px][c]*W[o][c][f].
//       mfma(A=W(M=o), B=xt(N=px)) -> acc r-consecutive = o-consecutive
//       -> direct 8 B bf16 stores via v_cvt_pk_bf16_f32, NO LDS round-trip.
// ---------------------------------------------------------------------------
__global__ __launch_bounds__(256) void k_convmetaG(
        const short* __restrict__ xt,
        const short* __restrict__ wc2, const short* __restrict__ wt3,
        const float* __restrict__ b_off, const float* __restrict__ b_mod,
        float4* __restrict__ metaW, int4* __restrict__ metaO,
        short* __restrict__ G) {
    __shared__ __align__(16) char smem[18432];       // window 13824 + s_out 4608
    float* s_out = (float*)(smem + 13824);           // [32ch][36]

    int tid  = threadIdx.x;
    int lane = tid & 63;
    int wv   = __builtin_amdgcn_readfirstlane((int)(tid >> 6));
    int blk  = blockIdx.x;                           // (b*64+i)*2 + half
    int b = blk >> 7, i = (blk >> 1) & 63, jb = (blk & 1) * 32;
    int P0 = blk * 32;
    const short* xs = xt + (size_t)b * 262144;
    int arow = lane & 15, cg = lane >> 4, cgb = cg * 8;

    // ---- ph1: stage 3 rows x 36 cells (zero-padded), swizzled 16 B chunks
    for (int u = tid; u < 864; u += 256) {           // 108 cells x 8 chunks
        int cell = u >> 3, chunk = u & 7;
        int r = cell / 36, cc = cell - r * 36;
        int y = i - 1 + r, gx = jb + cc - 2;
        short8v v = (short8v){0,0,0,0,0,0,0,0};
        if (((unsigned)y < 64u) & ((unsigned)gx < 64u))
            v = *(const short8v*)(xs + ((y << 6) + gx) * 64 + chunk * 8);
        *(short8v*)(smem + cell * 128 + ((chunk * 16) ^ ((cell & 7) << 4))) = v;
    }
    __syncthreads();

    // ---- ph2: conv. wave (mh = px-half, nh = ch-half); M=32 px, N=32 ch.
    {
        int mh = wv & 1, nh = wv >> 1;
        f32x4 acc = (f32x4){0.f, 0.f, 0.f, 0.f};
        #pragma unroll
        for (int ky = 0; ky < 3; ++ky)
            #pragma unroll
            for (int kx = 0; kx < 3; ++kx) {
                int f = ky * 3 + kx;
                #pragma unroll
                for (int kk = 0; kk < 2; ++kk) {
                    bf16x8 bq = *(const bf16x8*)(wc2 + (f * 32 + nh * 16 + arow) * 64
                                                 + kk * 32 + cgb);
                    int cell = ky * 36 + mh * 16 + arow + kx + 1;
                    const char* ap = smem + cell * 128
                                   + ((kk * 64 + cg * 16) ^ ((cell & 7) << 4));
                    acc = __builtin_amdgcn_mfma_f32_16x16x32_bf16(
                        *(const bf16x8*)ap, bq, acc, 0, 0, 0);
                }
            }
        #pragma unroll
        for (int r = 0; r < 4; ++r)
            s_out[(nh * 16 + arow) * 36 + mh * 16 + cg * 4 + r] = acc[r];
    }
    __syncthreads();

    // ---- ph3: bilinear meta (288 = 9 taps x 32 px), STRIDED
    for (int u = tid; u < 288; u += 256) {
        int f = u >> 5, p = u & 31;
        float dy = s_out[(2 * f)     * 36 + p] + b_off[2 * f];
        float dx = s_out[(2 * f + 1) * 36 + p] + b_off[2 * f + 1];
        float mv = s_out[(18 + f)    * 36 + p] + b_mod[f];
        float m  = 1.f / (1.f + expf(-mv));

        float ys  = (float)(i - 1 + f / 3) + dy;
        float xs2 = (float)(jb + p - 1 + f % 3) + dx;
        float y0f = floorf(ys), x0f = floorf(xs2);
        int   y0  = (int)y0f,   x0  = (int)x0f;
        float fy = ys - y0f, fx = xs2 - x0f;

        bool vy0 = (unsigned)y0       < 64u, vy1 = (unsigned)(y0 + 1) < 64u;
        bool vx0 = (unsigned)x0       < 64u, vx1 = (unsigned)(x0 + 1) < 64u;
        float w00 = (vy0 & vx0) ? (1.f - fy) * (1.f - fx) * m : 0.f;
        float w01 = (vy0 & vx1) ? (1.f - fy) * fx         * m : 0.f;
        float w10 = (vy1 & vx0) ? fy         * (1.f - fx) * m : 0.f;
        float w11 = (vy1 & vx1) ? fy         * fx         * m : 0.f;

        int y0c = min(max(y0, 0), 63), y1c = min(max(y0 + 1, 0), 63);
        int x0c = min(max(x0, 0), 63), x1c = min(max(x0 + 1, 0), 63);

        metaW[f * NPIX + P0 + p] = make_float4(w00, w01, w10, w11);
        metaO[f * NPIX + P0 + p] = make_int4(((y0c << 6) + x0c) * 128,
                                             ((y0c << 6) + x1c) * 128,
                                             ((y1c << 6) + x0c) * 128,
                                             ((y1c << 6) + x1c) * 128);
    }

    // ---- ph4: G-GEMM from center row (no barrier needed: window is stable)
    bf16x8 wfrag[9][2];
    #pragma unroll
    for (int f = 0; f < 9; ++f)
        #pragma unroll
        for (int kk = 0; kk < 2; ++kk)
            wfrag[f][kk] = *(const bf16x8*)(wt3 + ((wv * 18 + f * 2 + kk) * 64 + lane) * 8);

    #pragma unroll
    for (int f = 0; f < 9; ++f) {
        f32x4 g[2];
        g[0] = (f32x4){0.f, 0.f, 0.f, 0.f};
        g[1] = (f32x4){0.f, 0.f, 0.f, 0.f};
        #pragma unroll
        for (int kk = 0; kk < 2; ++kk)
            #pragma unroll
            for (int nf = 0; nf < 2; ++nf) {
                int cell = 36 + nf * 16 + arow + 2;  // center row, col jb+px
                const char* bp = smem + cell * 128
                               + ((kk * 64 + cg * 16) ^ ((cell & 7) << 4));
                g[nf] = __builtin_amdgcn_mfma_f32_16x16x32_bf16(
                    wfrag[f][kk], *(const bf16x8*)bp, g[nf], 0, 0, 0);
            }
        #pragma unroll
        for (int nf = 0; nf < 2; ++nf) {
            unsigned w0, w1;
            asm("v_cvt_pk_bf16_f32 %0, %1, %2" : "=v"(w0) : "v"(g[nf][0]), "v"(g[nf][1]));
            asm("v_cvt_pk_bf16_f32 %0, %1, %2" : "=v"(w1) : "v"(g[nf][2]), "v"(g[nf][3]));
            size_t base = (size_t)(f * NPIX + P0 + nf * 16 + arow) * 64 + wv * 16 + cg * 4;
            *(int2*)(G + base) = make_int2((int)w0, (int)w1);
        }
    }
}

// ---------------------------------------------------------------------------
// k_final: out[p][o] = bias[o] + sum_f sum_cn w[p,f,cn] * G_f[q(p,f,cn)][o].
// Grid 4096 (b = bid&7 -> XCD-batch L2 affinity), 256 thr / 4 waves, 2 px/wave.
// Paired-corner loads: lanes 0-31 = corner x0 row, lanes 32-63 = corner x1 row,
// 4 B/lane (2 ch) -> 2 loads per tap; single __shfl_xor(32) reduce at end.
// ---------------------------------------------------------------------------
__global__ __launch_bounds__(256, 4) void k_final(
        const short* __restrict__ G,
        const float4* __restrict__ metaW, const int4* __restrict__ metaO,
        const float* __restrict__ bias, float* __restrict__ out) {
    __shared__ float s_o[8][66];
    int tid  = threadIdx.x;
    int lane = tid & 63;
    int wv   = __builtin_amdgcn_readfirstlane((int)(tid >> 6));
    int bid  = blockIdx.x;
    int b = bid & 7, q = bid >> 3;                   // XCD k <- batch k
    int i = q >> 3, j0 = (q & 7) * 8;
    int P0 = b * 4096 + q * 8;
    int cp = lane & 31;
    bool hi = lane >= 32;
    const char* Gb = (const char*)G + (size_t)b * 524288;

    float a00 = 0.f, a01 = 0.f, a10 = 0.f, a11 = 0.f;
    #pragma unroll
    for (int pxi = 0; pxi < 2; ++pxi) {
        int P = P0 + wv * 2 + pxi;
        float accL = 0.f, accH = 0.f;
        #pragma unroll
        for (int f = 0; f < 9; ++f) {
            float4 mW = metaW[f * NPIX + P];         // wave-uniform -> s_load
            int4   mO = metaO[f * NPIX + P];
            const char* Gf = Gb + (size_t)f * 4194304;
            unsigned g0 = *(const unsigned*)(Gf + (hi ? mO.y : mO.x) + cp * 4);
            unsigned g1 = *(const unsigned*)(Gf + (hi ? mO.w : mO.z) + cp * 4);
            float wA = hi ? mW.y : mW.x;
            float wB = hi ? mW.w : mW.z;
            union { unsigned u; float f; } l0, h0, l1, h1;
            l0.u = g0 << 16; h0.u = g0 & 0xffff0000u;
            l1.u = g1 << 16; h1.u = g1 & 0xffff0000u;
            accL += wA * l0.f + wB * l1.f;
            accH += wA * h0.f + wB * h1.f;
        }
        if (pxi == 0) { a00 = accL; a01 = accH; }
        else          { a10 = accL; a11 = accH; }
    }
    a00 += __shfl_xor(a00, 32); a01 += __shfl_xor(a01, 32);
    a10 += __shfl_xor(a10, 32); a11 += __shfl_xor(a11, 32);
    if (!hi) {
        s_o[wv * 2 + 0][2 * cp] = a00; s_o[wv * 2 + 0][2 * cp + 1] = a01;
        s_o[wv * 2 + 1][2 * cp] = a10; s_o[wv * 2 + 1][2 * cp + 1] = a11;
    }
    __syncthreads();
    {
        int o = tid >> 2, jq = tid & 3;
        float bv = bias[o];
        float2 v;
        v.x = s_o[jq * 2 + 0][o] + bv;
        v.y = s_o[jq * 2 + 1][o] + bv;
        *(float2*)(out + ((size_t)(b * 64 + o)) * 4096 + i * 64 + j0 + jq * 2) = v;
    }
}

// ---------------------------------------------------------------------------
extern "C" void kernel_launch(void* const* d_in, const int* in_sizes, int n_in,
                              void* d_out, int out_size, void* d_ws, size_t ws_size,
                              hipStream_t stream) {
    const float* x     = (const float*)d_in[0];
    const float* w_off = (const float*)d_in[1];
    const float* b_off = (const float*)d_in[2];
    const float* w_mod = (const float*)d_in[3];
    const float* b_mod = (const float*)d_in[4];
    const float* w     = (const float*)d_in[5];
    const float* bias  = (const float*)d_in[6];
    float* out = (float*)d_out;

    char* ws = (char*)d_ws;
    short*  xt    = (short*)(ws);                    //  4,194,304 B
    short*  wt3   = (short*)(ws + 4194304);          //     73,728 B
    short*  wc2   = (short*)(ws + 4268032);          //     36,864 B
    float4* metaW = (float4*)(ws + 4304896);         //  4,718,592 B
    int4*   metaO = (int4*)(ws + 9023488);           //  4,718,592 B
    short*  G     = (short*)(ws + 13742080);         // 37,748,736 B

    hipLaunchKernelGGL(k_misc,      dim3(728),  dim3(256), 0, stream,
                       x, xt, w, w_off, w_mod, wt3, wc2);
    hipLaunchKernelGGL(k_convmetaG, dim3(1024), dim3(256), 0, stream,
                       xt, wc2, wt3, b_off, b_mod, metaW, metaO, G);
    hipLaunchKernelGGL(k_final,     dim3(4096), dim3(256), 0, stream,
                       G, metaW, metaO, bias, out);
}